// Round 1
// baseline (608.839 us; speedup 1.0000x reference)
//
#include <hip/hip_runtime.h>

// GumbelCodebook: y = one_hot(argmax(logits+gumbel)), z = codebook[argmax]
// Shapes: logits/gumbel [8,4096,2048] f32, codebook [2048,256] f32
// Outputs concatenated in d_out: z [8,4096,256] then y [8,4096,2048], f32.

#define NUM_CODES 2048
#define CODE_DIM  256
#define BLOCK     256
#define VECS_PER_THREAD 2   // 2 x float4 = 8 codes/thread * 256 threads = 2048

__global__ __launch_bounds__(BLOCK) void gumbel_codebook_kernel(
    const float* __restrict__ logits,
    const float* __restrict__ gumbel,
    const float* __restrict__ codebook,
    float* __restrict__ z_out,   // [tokens, CODE_DIM]
    float* __restrict__ y_out)   // [tokens, NUM_CODES]
{
    const int token = blockIdx.x;
    const int tid   = threadIdx.x;

    const size_t row_off = (size_t)token * NUM_CODES;
    const float4* lrow = (const float4*)(logits + row_off);
    const float4* grow = (const float4*)(gumbel + row_off);

    // --- per-thread argmax over 8 codes (increasing index order -> strict '>'
    // keeps the first occurrence, matching jnp.argmax tie-break) ---
    float best = -INFINITY;
    int bestIdx = NUM_CODES;  // sentinel larger than any real index
#pragma unroll
    for (int c = 0; c < VECS_PER_THREAD; ++c) {
        const int vec = c * BLOCK + tid;
        const int base = vec * 4;
        float4 l = lrow[vec];
        float4 g = grow[vec];
        float s0 = l.x + g.x;
        float s1 = l.y + g.y;
        float s2 = l.z + g.z;
        float s3 = l.w + g.w;
        if (s0 > best) { best = s0; bestIdx = base + 0; }
        if (s1 > best) { best = s1; bestIdx = base + 1; }
        if (s2 > best) { best = s2; bestIdx = base + 2; }
        if (s3 > best) { best = s3; bestIdx = base + 3; }
    }

    // --- wave-level (64-lane) argmax reduction; lower index wins ties ---
#pragma unroll
    for (int off = 32; off >= 1; off >>= 1) {
        float ob = __shfl_down(best, off, 64);
        int   oi = __shfl_down(bestIdx, off, 64);
        if (ob > best || (ob == best && oi < bestIdx)) { best = ob; bestIdx = oi; }
    }

    // --- cross-wave reduction through LDS (4 waves/block) ---
    __shared__ float s_val[4];
    __shared__ int   s_idx[4];
    __shared__ int   s_amax;
    const int wave = tid >> 6;
    const int lane = tid & 63;
    if (lane == 0) { s_val[wave] = best; s_idx[wave] = bestIdx; }
    __syncthreads();
    if (tid == 0) {
        float b = s_val[0];
        int bi = s_idx[0];
#pragma unroll
        for (int w = 1; w < 4; ++w) {
            float ob = s_val[w];
            int oi = s_idx[w];
            if (ob > b || (ob == b && oi < bi)) { b = ob; bi = oi; }
        }
        s_amax = bi;
    }
    __syncthreads();
    const int amax = s_amax;

    // --- write y (one-hot), vectorized zero stores with patch ---
    float4* yrow = (float4*)(y_out + row_off);
#pragma unroll
    for (int c = 0; c < VECS_PER_THREAD; ++c) {
        const int vec = c * BLOCK + tid;
        const int base = vec * 4;
        float4 out = make_float4(0.f, 0.f, 0.f, 0.f);
        if (amax >= base && amax < base + 4) {
            ((float*)&out)[amax - base] = 1.0f;
        }
        yrow[vec] = out;
    }

    // --- write z = codebook[amax], one float per thread (CODE_DIM==BLOCK) ---
    z_out[(size_t)token * CODE_DIM + tid] = codebook[(size_t)amax * CODE_DIM + tid];
}

extern "C" void kernel_launch(void* const* d_in, const int* in_sizes, int n_in,
                              void* d_out, int out_size, void* d_ws, size_t ws_size,
                              hipStream_t stream) {
    const float* logits   = (const float*)d_in[0];
    const float* gumbel   = (const float*)d_in[1];
    const float* codebook = (const float*)d_in[2];

    const int tokens = in_sizes[0] / NUM_CODES;  // 8*4096 = 32768

    float* z_out = (float*)d_out;                               // [tokens, 256]
    float* y_out = (float*)d_out + (size_t)tokens * CODE_DIM;   // [tokens, 2048]

    gumbel_codebook_kernel<<<tokens, BLOCK, 0, stream>>>(
        logits, gumbel, codebook, z_out, y_out);
}